// Round 16
// baseline (86.492 us; speedup 1.0000x reference)
//
#include <hip/hip_runtime.h>
#include <hip/hip_bf16.h>

// B=8, N=256, D=E=G=MID=OUT=128
#define B_ 8
#define N_ 256
#define C_ 128
#define S_ 8
#define STEPB (N_ * C_ * 4)   // 128KB per i-row of one batch

typedef __attribute__((ext_vector_type(4))) float f32x4;
typedef __attribute__((ext_vector_type(8))) short s16x8;

typedef __attribute__((address_space(1))) const void gas_void;
typedef __attribute__((address_space(3))) void las_void;

__device__ __forceinline__ unsigned short f2bf(float f) {
  unsigned int u = __builtin_bit_cast(unsigned int, f);
  u += 0x7FFFu + ((u >> 16) & 1u);   // RNE
  return (unsigned short)(u >> 16);
}

__device__ __forceinline__ unsigned int pk2(float a, float b) {
  __hip_bfloat162 h = __float22bfloat162_rn(make_float2(a, b));
  unsigned int u;
  __builtin_memcpy(&u, &h, 4);
  return u;
}

__device__ __forceinline__ s16x8 cvt8(f32x4 lo, f32x4 hi) {
  union { unsigned int u[4]; s16x8 s; } r;
  r.u[0] = pk2(lo[0], lo[1]);
  r.u[1] = pk2(lo[2], lo[3]);
  r.u[2] = pk2(hi[0], hi[1]);
  r.u[3] = pk2(hi[2], hi[3]);
  return r.s;
}

// ---------- P: ws_c, ws_mh2 (bf16 frag-packed), ws_B, ws_adj ----------
__global__ void k_pro(const float* __restrict__ node, const float* __restrict__ hidden,
                      const float* __restrict__ graph, const int* __restrict__ adjm,
                      const float* __restrict__ Wn, const float* __restrict__ bn,
                      const float* __restrict__ Wh, const float* __restrict__ bh,
                      const float* __restrict__ be,
                      const float* __restrict__ Wg, const float* __restrict__ bg,
                      const float* __restrict__ We,
                      float* __restrict__ ws_c, unsigned short* __restrict__ ws_mh2,
                      short* __restrict__ ws_B, unsigned char* __restrict__ ws_adj) {
  int bid = blockIdx.x, t = threadIdx.x;
  if (bid >= 544) {
    int base = (bid - 544) * 1024 + t * 8;
    int4 a = *reinterpret_cast<const int4*>(adjm + base);
    int4 c = *reinterpret_cast<const int4*>(adjm + base + 4);
    uint2 v;
    v.x = (unsigned)a.x | ((unsigned)a.y << 8) | ((unsigned)a.z << 16) | ((unsigned)a.w << 24);
    v.y = (unsigned)c.x | ((unsigned)c.y << 8) | ((unsigned)c.z << 16) | ((unsigned)c.w << 24);
    *reinterpret_cast<uint2*>(ws_adj + base) = v;
    return;
  }
  if (bid >= 512) {
    int f = bid - 512;                 // 0..31
    if (t < 64) {
      int kb = f >> 3, nbg = f & 7;
      int lr = t & 15, lg = t >> 4;
      s16x8 v;
#pragma unroll
      for (int e = 0; e < 8; ++e)
        v[e] = (short)f2bf(We[(kb * 32 + lg * 8 + e) * C_ + nbg * 16 + lr]);
      *reinterpret_cast<s16x8*>(ws_B + (f * 64 + t) * 8) = v;
    }
    return;
  }
  bool isc = bid < 256;
  int row0 = (isc ? bid : bid - 256) * 8;
  const float* src = isc ? node : hidden;
  const float* W   = isc ? Wn : Wh;
  __shared__ float sh[8][C_];
#pragma unroll
  for (int r = 0; r < 8; ++r) sh[r][t] = src[(row0 + r) * C_ + t];
  __syncthreads();
  float g = 0.f;
  float acc[8];
#pragma unroll
  for (int r = 0; r < 8; ++r) acc[r] = 0.f;
  const float* gr = graph + (row0 >> 8) * C_;
  for (int k = 0; k < C_; k += 8) {
    float wv[8];
#pragma unroll
    for (int u = 0; u < 8; ++u) wv[u] = W[(k + u) * C_ + t];
    if (isc) {
      float wgv[8];
#pragma unroll
      for (int u = 0; u < 8; ++u) wgv[u] = Wg[(k + u) * C_ + t];
#pragma unroll
      for (int u = 0; u < 8; ++u) g += gr[k + u] * wgv[u];
    }
#pragma unroll
    for (int u = 0; u < 8; ++u)
#pragma unroll
      for (int r = 0; r < 8; ++r) acc[r] += sh[r][k + u] * wv[u];
  }
  if (isc) {
    float init = bn[t] + be[t] + bg[t] + g;
#pragma unroll
    for (int r = 0; r < 8; ++r) ws_c[(row0 + r) * C_ + t] = acc[r] + init;
  } else {
    float init = bh[t];
    int p = (t >> 5) * 32 + (t & 15) * 2 + ((t >> 4) & 1);
#pragma unroll
    for (int r = 0; r < 8; ++r) ws_mh2[(row0 + r) * C_ + p] = f2bf(acc[r] + init);
  }
}

// ---------- Main: EXACT R12 (session-best, 75.7 total) ----------
// XCD-locality: b = wg&7 (one XCD owns one batch slice), j16 = (wg>>3)&15,
// s = wg>>7 with interleaved i = s+8T -> each XCD sweeps contiguous 1MB/step.
// 3-slot ring, 2 GLL16/step, vmcnt(2) steady; mh/adj staged ONCE in prologue.
// pbuf stays f32: R15 measured bf16-pbuf = +10us (sub-64B cross-XCD stores).
__global__ __launch_bounds__(256, 4) void k_main(
    const float* __restrict__ edge, const unsigned char* __restrict__ ws_adj,
    const short* __restrict__ ws_B,
    const float* __restrict__ ws_c, const unsigned short* __restrict__ ws_mh2,
    float* __restrict__ pbuf) {
  __shared__ __align__(16) char smem[3 * 8192 + 8192 + 512];
  char* ring    = smem;
  char* mh_lds  = smem + 24576;
  char* adj_lds = smem + 24576 + 8192;
  const int lane = threadIdx.x & 63;
  const int w = threadIdx.x >> 6;
  const int wg = blockIdx.x;
  const int b   = wg & 7;
  const int j16 = (wg >> 3) & 15;
  const int s   = wg >> 7;
  const int j0 = j16 * 16;
  const int n0 = w * 32;
  const int lr = lane & 15;
  const int lg = lane >> 4;

  s16x8 bfrag[4][2];
#pragma unroll
  for (int kb = 0; kb < 4; ++kb)
#pragma unroll
    for (int nb = 0; nb < 2; ++nb)
      bfrag[kb][nb] = *reinterpret_cast<const s16x8*>(
          ws_B + ((kb * 8 + w * 2 + nb) * 64 + lane) * 8);

  float cf[2][4];
#pragma unroll
  for (int nb = 0; nb < 2; ++nb)
#pragma unroll
    for (int r = 0; r < 4; ++r)
      cf[nb][r] = ws_c[(b * N_ + j0 + lg * 4 + r) * C_ + n0 + nb * 16 + lr];

  f32x4 mx[2];
#pragma unroll
  for (int nb = 0; nb < 2; ++nb)
#pragma unroll
    for (int r = 0; r < 4; ++r) mx[nb][r] = -INFINITY;

  const char* gedge = (const char*)(edge + ((size_t)(b * N_ + s) * N_ + j0) * C_);

  int soff[2];
#pragma unroll
  for (int q = 0; q < 2; ++q) {
    int y = w * 2048 + q * 1024 + lane * 16;
    int row = y >> 9;
    soff[q] = y ^ ((row & 7) << 4);
  }
  const int base0 = lr * 512 + lg * 32;
  const int swz = (lr & 7) << 4;

#define GLL16(GP, LP) __builtin_amdgcn_global_load_lds((gas_void*)(GP), (las_void*)(LP), 16, 0, 0)
#define GLL4(GP, LP)  __builtin_amdgcn_global_load_lds((gas_void*)(GP), (las_void*)(LP), 4, 0, 0)

#define ISSUE(SL, TT) do { \
    const char* gch = gedge + (size_t)(TT) * 8 * STEPB; \
    char* lb = ring + (SL) * 8192 + w * 2048; \
    GLL16(gch + soff[0], lb); \
    GLL16(gch + soff[1], lb + 1024); \
  } while (0)

#define STEP(SL, ISL, WAITN, DOISSUE, TI, T) do { \
    asm volatile("s_waitcnt vmcnt(" WAITN ")\n\ts_barrier" ::: "memory"); \
    if (DOISSUE) ISSUE(ISL, TI); \
    const char* rb = ring + (SL) * 8192; \
    s16x8 af[4]; \
    _Pragma("unroll") \
    for (int kb = 0; kb < 4; ++kb) { \
      int a0 = (base0 + kb * 128) ^ swz; \
      f32x4 lo = *reinterpret_cast<const f32x4*>(rb + a0); \
      f32x4 hi = *reinterpret_cast<const f32x4*>(rb + (a0 ^ 16)); \
      af[kb] = cvt8(lo, hi); \
    } \
    unsigned int mw = *reinterpret_cast<const unsigned int*>(mh_lds + (T) * 256 + w * 64 + lr * 4); \
    unsigned int ab = *reinterpret_cast<const unsigned int*>(adj_lds + (T) * 16 + lg * 4); \
    float mh0 = __builtin_bit_cast(float, mw << 16); \
    float mh1 = __builtin_bit_cast(float, mw & 0xffff0000u); \
    float adjf[4] = {(float)(ab & 0xff), (float)((ab >> 8) & 0xff), \
                     (float)((ab >> 16) & 0xff), (float)(ab >> 24)}; \
    _Pragma("unroll") \
    for (int nb = 0; nb < 2; ++nb) { \
      f32x4 acc; \
      float mhv = nb ? mh1 : mh0; \
      _Pragma("unroll") \
      for (int r = 0; r < 4; ++r) acc[r] = cf[nb][r] + mhv; \
      _Pragma("unroll") \
      for (int kb = 0; kb < 4; ++kb) \
        acc = __builtin_amdgcn_mfma_f32_16x16x32_bf16(af[kb], bfrag[kb][nb], acc, 0, 0, 0); \
      _Pragma("unroll") \
      for (int r = 0; r < 4; ++r) mx[nb][r] = fmaxf(mx[nb][r], adjf[r] * acc[r]); \
    } \
  } while (0)

  {
    const char* mh_g = (const char*)(ws_mh2 + (size_t)b * N_ * C_);
#pragma unroll
    for (int q = 0; q < 2; ++q) {
      int T = w * 8 + q * 4 + (lane >> 4);
      GLL16(mh_g + ((size_t)(s + 8 * T)) * 256 + (lane & 15) * 16,
            mh_lds + w * 2048 + q * 1024);
    }
    const char* adj_g = (const char*)(ws_adj + (size_t)b * N_ * N_ + j0);
    GLL4(adj_g + ((size_t)(s + 8 * (lane >> 2))) * N_ + (lane & 3) * 4, adj_lds);
    GLL4(adj_g + ((size_t)(s + 8 * (16 + (lane >> 2)))) * N_ + (lane & 3) * 4, adj_lds + 256);
  }
  ISSUE(0, 0);
  ISSUE(1, 1);
  asm volatile("s_waitcnt vmcnt(4)\n\ts_barrier" ::: "memory");

  for (int o = 0; o < 10; ++o) {
    STEP(0, 2, "2", 1, 3 * o + 2, 3 * o);
    STEP(1, 0, "2", 1, 3 * o + 3, 3 * o + 1);
    STEP(2, 1, "2", 1, 3 * o + 4, 3 * o + 2);
  }
  STEP(0, 2, "2", 0, 0, 30);
  STEP(1, 0, "0", 0, 0, 31);

#undef STEP
#undef ISSUE
#undef GLL16
#undef GLL4

  float* prow = pbuf + (((size_t)s * B_ + b) * N_ + j0 + lg * 4) * C_ + n0 + lr;
#pragma unroll
  for (int nb = 0; nb < 2; ++nb)
#pragma unroll
    for (int r = 0; r < 4; ++r)
      prow[r * C_ + nb * 16] = mx[nb][r];
}

// ---------- Epilogue: S-max + node@Wo1 + hidden@Wo2 + msgs@Wo3 (R12-proven) ----------
__global__ void k_epi(const float* __restrict__ node, const float* __restrict__ hidden,
                      const float* __restrict__ Wo1, const float* __restrict__ bo1,
                      const float* __restrict__ Wo2, const float* __restrict__ bo2,
                      const float* __restrict__ Wo3, const float* __restrict__ bo3,
                      const float* __restrict__ pbuf, float* __restrict__ out) {
  int row0 = blockIdx.x * 4;
  int col = threadIdx.x & 127;
  int half = threadIdx.x >> 7;
  __shared__ float shn[4][C_], shh[4][C_], shm[4][C_];
#pragma unroll
  for (int r = 0; r < 2; ++r) {
    int rr = half * 2 + r;
    shn[rr][col] = node[(row0 + rr) * C_ + col];
    shh[rr][col] = hidden[(row0 + rr) * C_ + col];
    float mv = -INFINITY;
#pragma unroll
    for (int s = 0; s < S_; ++s)
      mv = fmaxf(mv, pbuf[((size_t)s * (B_ * N_) + row0 + rr) * C_ + col]);
    shm[rr][col] = mv;
  }
  __syncthreads();
  float init = bo1[col] + bo2[col] + bo3[col];
  float acc[2];
  acc[0] = init; acc[1] = init;
  for (int k = 0; k < C_; k += 8) {
    float wv1[8], wv2[8], wv3[8];
#pragma unroll
    for (int u = 0; u < 8; ++u) {
      wv1[u] = Wo1[(k + u) * C_ + col];
      wv2[u] = Wo2[(k + u) * C_ + col];
      wv3[u] = Wo3[(k + u) * C_ + col];
    }
#pragma unroll
    for (int u = 0; u < 8; ++u)
#pragma unroll
      for (int r = 0; r < 2; ++r) {
        int rr = half * 2 + r;
        acc[r] += shn[rr][k + u] * wv1[u] + shh[rr][k + u] * wv2[u] + shm[rr][k + u] * wv3[u];
      }
  }
#pragma unroll
  for (int r = 0; r < 2; ++r)
    out[(row0 + half * 2 + r) * C_ + col] = acc[r];
}

extern "C" void kernel_launch(void* const* d_in, const int* in_sizes, int n_in,
                              void* d_out, int out_size, void* d_ws, size_t ws_size,
                              hipStream_t stream) {
  const float* node   = (const float*)d_in[0];
  const float* edge   = (const float*)d_in[1];
  const float* graph  = (const float*)d_in[2];
  const int*   adjm   = (const int*)d_in[3];
  const float* hidden = (const float*)d_in[4];
  const float* Wn = (const float*)d_in[5];  const float* bn = (const float*)d_in[6];
  const float* Wh = (const float*)d_in[7];  const float* bh = (const float*)d_in[8];
  const float* We = (const float*)d_in[9];  const float* be = (const float*)d_in[10];
  const float* Wg = (const float*)d_in[11]; const float* bg = (const float*)d_in[12];
  const float* Wo1 = (const float*)d_in[13]; const float* bo1 = (const float*)d_in[14];
  const float* Wo2 = (const float*)d_in[15]; const float* bo2 = (const float*)d_in[16];
  const float* Wo3 = (const float*)d_in[17]; const float* bo3 = (const float*)d_in[18];
  float* out = (float*)d_out;

  char* ws = (char*)d_ws;
  float*          ws_c   = (float*)ws;                            // 1 MB
  unsigned short* ws_mh2 = (unsigned short*)(ws + (1u << 20));    // 512 KB (bf16)
  short*          ws_B   = (short*)(ws + 1572864u);               // 32 KB
  unsigned char*  ws_adj = (unsigned char*)(ws + 1835008u);       // 512 KB
  float*          pbuf   = (float*)(ws + (4u << 20));             // 8 MB partials (f32)

  k_pro<<<1056, 128, 0, stream>>>(node, hidden, graph, adjm, Wn, bn, Wh, bh, be,
                                  Wg, bg, We, ws_c, ws_mh2, ws_B, ws_adj);
  k_main<<<1024, 256, 0, stream>>>(edge, ws_adj, ws_B, ws_c, ws_mh2, pbuf);
  k_epi<<<512, 256, 0, stream>>>(node, hidden, Wo1, bo1, Wo2, bo2, Wo3, bo3,
                                 pbuf, out);
}

// Round 17
// 85.450 us; speedup vs baseline: 1.0122x; 1.0122x over previous
//
#include <hip/hip_runtime.h>
#include <hip/hip_bf16.h>

// B=8, N=256, D=E=G=MID=OUT=128
#define B_ 8
#define N_ 256
#define C_ 128
#define S_ 8
#define STEPB (N_ * C_ * 4)   // 128KB per i-row of one batch

typedef __attribute__((ext_vector_type(4))) float f32x4;
typedef __attribute__((ext_vector_type(8))) short s16x8;

typedef __attribute__((address_space(1))) const void gas_void;
typedef __attribute__((address_space(3))) void las_void;

__device__ __forceinline__ unsigned short f2bf(float f) {
  unsigned int u = __builtin_bit_cast(unsigned int, f);
  u += 0x7FFFu + ((u >> 16) & 1u);   // RNE
  return (unsigned short)(u >> 16);
}

__device__ __forceinline__ unsigned int pk2(float a, float b) {
  __hip_bfloat162 h = __float22bfloat162_rn(make_float2(a, b));
  unsigned int u;
  __builtin_memcpy(&u, &h, 4);
  return u;
}

__device__ __forceinline__ s16x8 cvt8(f32x4 lo, f32x4 hi) {
  union { unsigned int u[4]; s16x8 s; } r;
  r.u[0] = pk2(lo[0], lo[1]);
  r.u[1] = pk2(lo[2], lo[3]);
  r.u[2] = pk2(hi[0], hi[1]);
  r.u[3] = pk2(hi[2], hi[3]);
  return r.s;
}

// ---------- P: ws_c, ws_mh2 (bf16 frag-packed), ws_B, ws_adj (proven 8.6us) ----------
__global__ void k_pro(const float* __restrict__ node, const float* __restrict__ hidden,
                      const float* __restrict__ graph, const int* __restrict__ adjm,
                      const float* __restrict__ Wn, const float* __restrict__ bn,
                      const float* __restrict__ Wh, const float* __restrict__ bh,
                      const float* __restrict__ be,
                      const float* __restrict__ Wg, const float* __restrict__ bg,
                      const float* __restrict__ We,
                      float* __restrict__ ws_c, unsigned short* __restrict__ ws_mh2,
                      short* __restrict__ ws_B, unsigned char* __restrict__ ws_adj) {
  int bid = blockIdx.x, t = threadIdx.x;
  if (bid >= 544) {
    int base = (bid - 544) * 1024 + t * 8;
    int4 a = *reinterpret_cast<const int4*>(adjm + base);
    int4 c = *reinterpret_cast<const int4*>(adjm + base + 4);
    uint2 v;
    v.x = (unsigned)a.x | ((unsigned)a.y << 8) | ((unsigned)a.z << 16) | ((unsigned)a.w << 24);
    v.y = (unsigned)c.x | ((unsigned)c.y << 8) | ((unsigned)c.z << 16) | ((unsigned)c.w << 24);
    *reinterpret_cast<uint2*>(ws_adj + base) = v;
    return;
  }
  if (bid >= 512) {
    int f = bid - 512;                 // 0..31
    if (t < 64) {
      int kb = f >> 3, nbg = f & 7;
      int lr = t & 15, lg = t >> 4;
      s16x8 v;
#pragma unroll
      for (int e = 0; e < 8; ++e)
        v[e] = (short)f2bf(We[(kb * 32 + lg * 8 + e) * C_ + nbg * 16 + lr]);
      *reinterpret_cast<s16x8*>(ws_B + (f * 64 + t) * 8) = v;
    }
    return;
  }
  bool isc = bid < 256;
  int row0 = (isc ? bid : bid - 256) * 8;
  const float* src = isc ? node : hidden;
  const float* W   = isc ? Wn : Wh;
  __shared__ float sh[8][C_];
#pragma unroll
  for (int r = 0; r < 8; ++r) sh[r][t] = src[(row0 + r) * C_ + t];
  __syncthreads();
  float g = 0.f;
  float acc[8];
#pragma unroll
  for (int r = 0; r < 8; ++r) acc[r] = 0.f;
  const float* gr = graph + (row0 >> 8) * C_;
  for (int k = 0; k < C_; k += 8) {
    float wv[8];
#pragma unroll
    for (int u = 0; u < 8; ++u) wv[u] = W[(k + u) * C_ + t];
    if (isc) {
      float wgv[8];
#pragma unroll
      for (int u = 0; u < 8; ++u) wgv[u] = Wg[(k + u) * C_ + t];
#pragma unroll
      for (int u = 0; u < 8; ++u) g += gr[k + u] * wgv[u];
    }
#pragma unroll
    for (int u = 0; u < 8; ++u)
#pragma unroll
      for (int r = 0; r < 8; ++r) acc[r] += sh[r][k + u] * wv[u];
  }
  if (isc) {
    float init = bn[t] + be[t] + bg[t] + g;
#pragma unroll
    for (int r = 0; r < 8; ++r) ws_c[(row0 + r) * C_ + t] = acc[r] + init;
  } else {
    float init = bh[t];
    int p = (t >> 5) * 32 + (t & 15) * 2 + ((t >> 4) & 1);
#pragma unroll
    for (int r = 0; r < 8; ++r) ws_mh2[(row0 + r) * C_ + p] = f2bf(acc[r] + init);
  }
}

// ---------- Main: 16KB-contiguous-chunk variant ----------
// 512 blocks x 512 thr (8 waves = jh(2) x wq(4)). Block = (b, j32, s); per step
// reads edge[b][s+8T][j0..j0+32)[*] = 16KB CONTIGUOUS (2x the 8KB of R12).
// Same pipeline: 3-slot ring, 2 GLL16/wave/step, vmcnt(2), 1 barrier/step.
// XCD-locality: b = wg&7; per step an XCD sweeps a contiguous 1MB window.
__global__ __launch_bounds__(512, 4) void k_main(
    const float* __restrict__ edge, const unsigned char* __restrict__ ws_adj,
    const short* __restrict__ ws_B,
    const float* __restrict__ ws_c, const unsigned short* __restrict__ ws_mh2,
    float* __restrict__ pbuf) {
  __shared__ __align__(16) char smem[3 * 16384 + 8192 + 1024];  // 58368 B
  char* ring    = smem;
  char* mh_lds  = smem + 49152;
  char* adj_lds = smem + 49152 + 8192;
  const int lane = threadIdx.x & 63;
  const int w  = threadIdx.x >> 6;   // 0..7
  const int wq = w & 3;              // col chunk: n0 = wq*32
  const int jh = w >> 2;             // j half: rows jh*16..+16
  const int wg = blockIdx.x;
  const int b   = wg & 7;            // XCD-aligned batch
  const int j32 = (wg >> 3) & 7;
  const int s   = wg >> 6;           // i-interleave: i = s + 8T
  const int j0 = j32 * 32;
  const int n0 = wq * 32;
  const int lr = lane & 15;
  const int lg = lane >> 4;

  s16x8 bfrag[4][2];
#pragma unroll
  for (int kb = 0; kb < 4; ++kb)
#pragma unroll
    for (int nb = 0; nb < 2; ++nb)
      bfrag[kb][nb] = *reinterpret_cast<const s16x8*>(
          ws_B + ((kb * 8 + wq * 2 + nb) * 64 + lane) * 8);

  float cf[2][4];
#pragma unroll
  for (int nb = 0; nb < 2; ++nb)
#pragma unroll
    for (int r = 0; r < 4; ++r)
      cf[nb][r] = ws_c[(b * N_ + j0 + jh * 16 + lg * 4 + r) * C_ + n0 + nb * 16 + lr];

  f32x4 mx[2];
#pragma unroll
  for (int nb = 0; nb < 2; ++nb)
#pragma unroll
    for (int r = 0; r < 4; ++r) mx[nb][r] = -INFINITY;

  const char* gedge = (const char*)(edge + ((size_t)(b * N_ + s) * N_ + j0) * C_);

  // staging: 8 waves x 2KB cover the 16KB chunk; inverse-swizzled global src
  int soff[2];
#pragma unroll
  for (int q = 0; q < 2; ++q) {
    int y = w * 2048 + q * 1024 + lane * 16;  // linear LDS byte in slot
    int row = y >> 9;
    soff[q] = y ^ ((row & 7) << 4);
  }
  const int base0 = (jh * 16 + lr) * 512 + lg * 32;
  const int swz = (lr & 7) << 4;

#define GLL16(GP, LP) __builtin_amdgcn_global_load_lds((gas_void*)(GP), (las_void*)(LP), 16, 0, 0)

#define ISSUE(SL, TT) do { \
    const char* gch = gedge + (size_t)(TT) * 8 * STEPB; \
    char* lb = ring + (SL) * 16384 + w * 2048; \
    GLL16(gch + soff[0], lb); \
    GLL16(gch + soff[1], lb + 1024); \
  } while (0)

#define STEP(SL, ISL, WAITN, DOISSUE, TI, T) do { \
    asm volatile("s_waitcnt vmcnt(" WAITN ")\n\ts_barrier" ::: "memory"); \
    if (DOISSUE) ISSUE(ISL, TI); \
    const char* rb = ring + (SL) * 16384; \
    s16x8 af[4]; \
    _Pragma("unroll") \
    for (int kb = 0; kb < 4; ++kb) { \
      int a0 = (base0 + kb * 128) ^ swz; \
      f32x4 lo = *reinterpret_cast<const f32x4*>(rb + a0); \
      f32x4 hi = *reinterpret_cast<const f32x4*>(rb + (a0 ^ 16)); \
      af[kb] = cvt8(lo, hi); \
    } \
    unsigned int mw = *reinterpret_cast<const unsigned int*>(mh_lds + (T) * 256 + wq * 64 + lr * 4); \
    unsigned int ab = *reinterpret_cast<const unsigned int*>(adj_lds + (T) * 32 + jh * 16 + lg * 4); \
    float mh0 = __builtin_bit_cast(float, mw << 16); \
    float mh1 = __builtin_bit_cast(float, mw & 0xffff0000u); \
    float adjf[4] = {(float)(ab & 0xff), (float)((ab >> 8) & 0xff), \
                     (float)((ab >> 16) & 0xff), (float)(ab >> 24)}; \
    _Pragma("unroll") \
    for (int nb = 0; nb < 2; ++nb) { \
      f32x4 acc; \
      float mhv = nb ? mh1 : mh0; \
      _Pragma("unroll") \
      for (int r = 0; r < 4; ++r) acc[r] = cf[nb][r] + mhv; \
      _Pragma("unroll") \
      for (int kb = 0; kb < 4; ++kb) \
        acc = __builtin_amdgcn_mfma_f32_16x16x32_bf16(af[kb], bfrag[kb][nb], acc, 0, 0, 0); \
      _Pragma("unroll") \
      for (int r = 0; r < 4; ++r) mx[nb][r] = fmaxf(mx[nb][r], adjf[r] * acc[r]); \
    } \
  } while (0)

  {
    // mh rows T = w*4 + (lane>>4), i = s+8T: one GLL16 per wave -> mh_lds linear
    const char* mh_g = (const char*)(ws_mh2 + (size_t)b * N_ * C_);
    int T = w * 4 + (lane >> 4);
    GLL16(mh_g + ((size_t)(s + 8 * T)) * 256 + (lane & 15) * 16, mh_lds + w * 1024);
    // adj rows (32B each): lane stages row lane>>1; all 8 waves duplicate (benign)
    const char* adj_g = (const char*)(ws_adj + (size_t)b * N_ * N_ + j0);
    GLL16(adj_g + ((size_t)(s + 8 * (lane >> 1))) * N_ + (lane & 1) * 16, adj_lds);
  }
  ISSUE(0, 0);
  ISSUE(1, 1);
  // per wave: mh 1 + adj 1 + gen0 2 + gen1 2 = 6; vmcnt(4) -> mh,adj landed
  asm volatile("s_waitcnt vmcnt(4)\n\ts_barrier" ::: "memory");

  for (int o = 0; o < 10; ++o) {
    STEP(0, 2, "2", 1, 3 * o + 2, 3 * o);
    STEP(1, 0, "2", 1, 3 * o + 3, 3 * o + 1);
    STEP(2, 1, "2", 1, 3 * o + 4, 3 * o + 2);
  }
  STEP(0, 2, "2", 0, 0, 30);
  STEP(1, 0, "0", 0, 0, 31);

#undef STEP
#undef ISSUE
#undef GLL16

  float* prow = pbuf + (((size_t)s * B_ + b) * N_ + j0 + jh * 16 + lg * 4) * C_ + n0 + lr;
#pragma unroll
  for (int nb = 0; nb < 2; ++nb)
#pragma unroll
    for (int r = 0; r < 4; ++r)
      prow[r * C_ + nb * 16] = mx[nb][r];
}

// ---------- Epilogue: S-max + node@Wo1 + hidden@Wo2 + msgs@Wo3 (proven 8.7us) ----------
__global__ void k_epi(const float* __restrict__ node, const float* __restrict__ hidden,
                      const float* __restrict__ Wo1, const float* __restrict__ bo1,
                      const float* __restrict__ Wo2, const float* __restrict__ bo2,
                      const float* __restrict__ Wo3, const float* __restrict__ bo3,
                      const float* __restrict__ pbuf, float* __restrict__ out) {
  int row0 = blockIdx.x * 4;
  int col = threadIdx.x & 127;
  int half = threadIdx.x >> 7;
  __shared__ float shn[4][C_], shh[4][C_], shm[4][C_];
#pragma unroll
  for (int r = 0; r < 2; ++r) {
    int rr = half * 2 + r;
    shn[rr][col] = node[(row0 + rr) * C_ + col];
    shh[rr][col] = hidden[(row0 + rr) * C_ + col];
    float mv = -INFINITY;
#pragma unroll
    for (int s = 0; s < S_; ++s)
      mv = fmaxf(mv, pbuf[((size_t)s * (B_ * N_) + row0 + rr) * C_ + col]);
    shm[rr][col] = mv;
  }
  __syncthreads();
  float init = bo1[col] + bo2[col] + bo3[col];
  float acc[2];
  acc[0] = init; acc[1] = init;
  for (int k = 0; k < C_; k += 8) {
    float wv1[8], wv2[8], wv3[8];
#pragma unroll
    for (int u = 0; u < 8; ++u) {
      wv1[u] = Wo1[(k + u) * C_ + col];
      wv2[u] = Wo2[(k + u) * C_ + col];
      wv3[u] = Wo3[(k + u) * C_ + col];
    }
#pragma unroll
    for (int u = 0; u < 8; ++u)
#pragma unroll
      for (int r = 0; r < 2; ++r) {
        int rr = half * 2 + r;
        acc[r] += shn[rr][k + u] * wv1[u] + shh[rr][k + u] * wv2[u] + shm[rr][k + u] * wv3[u];
      }
  }
#pragma unroll
  for (int r = 0; r < 2; ++r)
    out[(row0 + half * 2 + r) * C_ + col] = acc[r];
}

extern "C" void kernel_launch(void* const* d_in, const int* in_sizes, int n_in,
                              void* d_out, int out_size, void* d_ws, size_t ws_size,
                              hipStream_t stream) {
  const float* node   = (const float*)d_in[0];
  const float* edge   = (const float*)d_in[1];
  const float* graph  = (const float*)d_in[2];
  const int*   adjm   = (const int*)d_in[3];
  const float* hidden = (const float*)d_in[4];
  const float* Wn = (const float*)d_in[5];  const float* bn = (const float*)d_in[6];
  const float* Wh = (const float*)d_in[7];  const float* bh = (const float*)d_in[8];
  const float* We = (const float*)d_in[9];  const float* be = (const float*)d_in[10];
  const float* Wg = (const float*)d_in[11]; const float* bg = (const float*)d_in[12];
  const float* Wo1 = (const float*)d_in[13]; const float* bo1 = (const float*)d_in[14];
  const float* Wo2 = (const float*)d_in[15]; const float* bo2 = (const float*)d_in[16];
  const float* Wo3 = (const float*)d_in[17]; const float* bo3 = (const float*)d_in[18];
  float* out = (float*)d_out;

  char* ws = (char*)d_ws;
  float*          ws_c   = (float*)ws;                            // 1 MB
  unsigned short* ws_mh2 = (unsigned short*)(ws + (1u << 20));    // 512 KB (bf16)
  short*          ws_B   = (short*)(ws + 1572864u);               // 32 KB
  unsigned char*  ws_adj = (unsigned char*)(ws + 1835008u);       // 512 KB
  float*          pbuf   = (float*)(ws + (4u << 20));             // 8 MB partials (f32)

  k_pro<<<1056, 128, 0, stream>>>(node, hidden, graph, adjm, Wn, bn, Wh, bh, be,
                                  Wg, bg, We, ws_c, ws_mh2, ws_B, ws_adj);
  k_main<<<512, 512, 0, stream>>>(edge, ws_adj, ws_B, ws_c, ws_mh2, pbuf);
  k_epi<<<512, 256, 0, stream>>>(node, hidden, Wo1, bo1, Wo2, bo2, Wo3, bo3,
                                 pbuf, out);
}

// Round 18
// 78.755 us; speedup vs baseline: 1.0982x; 1.0850x over previous
//
#include <hip/hip_runtime.h>
#include <hip/hip_bf16.h>

// B=8, N=256, D=E=G=MID=OUT=128
#define B_ 8
#define N_ 256
#define C_ 128
#define S_ 8
#define STEPB (N_ * C_ * 4)   // 128KB per i-row of one batch

typedef __attribute__((ext_vector_type(4))) float f32x4;
typedef __attribute__((ext_vector_type(8))) short s16x8;

typedef __attribute__((address_space(1))) const void gas_void;
typedef __attribute__((address_space(3))) void las_void;

__device__ __forceinline__ unsigned short f2bf(float f) {
  unsigned int u = __builtin_bit_cast(unsigned int, f);
  u += 0x7FFFu + ((u >> 16) & 1u);   // RNE
  return (unsigned short)(u >> 16);
}

__device__ __forceinline__ unsigned int pk2(float a, float b) {
  __hip_bfloat162 h = __float22bfloat162_rn(make_float2(a, b));
  unsigned int u;
  __builtin_memcpy(&u, &h, 4);
  return u;
}

__device__ __forceinline__ s16x8 cvt8(f32x4 lo, f32x4 hi) {
  union { unsigned int u[4]; s16x8 s; } r;
  r.u[0] = pk2(lo[0], lo[1]);
  r.u[1] = pk2(lo[2], lo[3]);
  r.u[2] = pk2(hi[0], hi[1]);
  r.u[3] = pk2(hi[2], hi[3]);
  return r.s;
}

// ---------- P: ws_c, ws_mh2 (bf16 frag-packed), ws_B, ws_adj, ws_zero ----------
__global__ void k_pro(const float* __restrict__ node, const float* __restrict__ hidden,
                      const float* __restrict__ graph, const int* __restrict__ adjm,
                      const float* __restrict__ Wn, const float* __restrict__ bn,
                      const float* __restrict__ Wh, const float* __restrict__ bh,
                      const float* __restrict__ be,
                      const float* __restrict__ Wg, const float* __restrict__ bg,
                      const float* __restrict__ We,
                      float* __restrict__ ws_c, unsigned short* __restrict__ ws_mh2,
                      short* __restrict__ ws_B, unsigned char* __restrict__ ws_adj,
                      float* __restrict__ ws_zero) {
  int bid = blockIdx.x, t = threadIdx.x;
  if (bid >= 1056) {
    ((float2*)ws_zero)[t] = make_float2(0.f, 0.f);   // 128 thr x 8B = 1KB zeros
    return;
  }
  if (bid >= 544) {
    int base = (bid - 544) * 1024 + t * 8;
    int4 a = *reinterpret_cast<const int4*>(adjm + base);
    int4 c = *reinterpret_cast<const int4*>(adjm + base + 4);
    uint2 v;
    v.x = (unsigned)a.x | ((unsigned)a.y << 8) | ((unsigned)a.z << 16) | ((unsigned)a.w << 24);
    v.y = (unsigned)c.x | ((unsigned)c.y << 8) | ((unsigned)c.z << 16) | ((unsigned)c.w << 24);
    *reinterpret_cast<uint2*>(ws_adj + base) = v;
    return;
  }
  if (bid >= 512) {
    int f = bid - 512;                 // 0..31
    if (t < 64) {
      int kb = f >> 3, nbg = f & 7;
      int lr = t & 15, lg = t >> 4;
      s16x8 v;
#pragma unroll
      for (int e = 0; e < 8; ++e)
        v[e] = (short)f2bf(We[(kb * 32 + lg * 8 + e) * C_ + nbg * 16 + lr]);
      *reinterpret_cast<s16x8*>(ws_B + (f * 64 + t) * 8) = v;
    }
    return;
  }
  bool isc = bid < 256;
  int row0 = (isc ? bid : bid - 256) * 8;
  const float* src = isc ? node : hidden;
  const float* W   = isc ? Wn : Wh;
  __shared__ float sh[8][C_];
#pragma unroll
  for (int r = 0; r < 8; ++r) sh[r][t] = src[(row0 + r) * C_ + t];
  __syncthreads();
  float g = 0.f;
  float acc[8];
#pragma unroll
  for (int r = 0; r < 8; ++r) acc[r] = 0.f;
  const float* gr = graph + (row0 >> 8) * C_;
  for (int k = 0; k < C_; k += 8) {
    float wv[8];
#pragma unroll
    for (int u = 0; u < 8; ++u) wv[u] = W[(k + u) * C_ + t];
    if (isc) {
      float wgv[8];
#pragma unroll
      for (int u = 0; u < 8; ++u) wgv[u] = Wg[(k + u) * C_ + t];
#pragma unroll
      for (int u = 0; u < 8; ++u) g += gr[k + u] * wgv[u];
    }
#pragma unroll
    for (int u = 0; u < 8; ++u)
#pragma unroll
      for (int r = 0; r < 8; ++r) acc[r] += sh[r][k + u] * wv[u];
  }
  if (isc) {
    float init = bn[t] + be[t] + bg[t] + g;
#pragma unroll
    for (int r = 0; r < 8; ++r) ws_c[(row0 + r) * C_ + t] = acc[r] + init;
  } else {
    float init = bh[t];
    int p = (t >> 5) * 32 + (t & 15) * 2 + ((t >> 4) & 1);
#pragma unroll
    for (int r = 0; r < 8; ++r) ws_mh2[(row0 + r) * C_ + p] = f2bf(acc[r] + init);
  }
}

// ---------- Main: R12 structure + ADJ-MASKED LOAD SKIP ----------
// New: steady-state ISSUEs redirect each lane's 512B j-row load to a 1KB
// zeroed dummy (L2-resident) when adj[b,i,j]==0 (~50% of rows). The compute
// path already multiplies by adjf in {0,1} before the max, so masked rows
// contribute exactly 0 == reference's 0*msgs. Edge HBM traffic ~53%.
__global__ __launch_bounds__(256, 4) void k_main(
    const float* __restrict__ edge, const unsigned char* __restrict__ ws_adj,
    const short* __restrict__ ws_B,
    const float* __restrict__ ws_c, const unsigned short* __restrict__ ws_mh2,
    const float* __restrict__ ws_zero, float* __restrict__ pbuf) {
  __shared__ __align__(16) char smem[3 * 8192 + 8192 + 512];
  char* ring    = smem;
  char* mh_lds  = smem + 24576;
  char* adj_lds = smem + 24576 + 8192;
  const int lane = threadIdx.x & 63;
  const int w = threadIdx.x >> 6;
  const int wg = blockIdx.x;
  const int b   = wg & 7;
  const int j16 = (wg >> 3) & 15;
  const int s   = wg >> 7;
  const int j0 = j16 * 16;
  const int n0 = w * 32;
  const int lr = lane & 15;
  const int lg = lane >> 4;

  s16x8 bfrag[4][2];
#pragma unroll
  for (int kb = 0; kb < 4; ++kb)
#pragma unroll
    for (int nb = 0; nb < 2; ++nb)
      bfrag[kb][nb] = *reinterpret_cast<const s16x8*>(
          ws_B + ((kb * 8 + w * 2 + nb) * 64 + lane) * 8);

  float cf[2][4];
#pragma unroll
  for (int nb = 0; nb < 2; ++nb)
#pragma unroll
    for (int r = 0; r < 4; ++r)
      cf[nb][r] = ws_c[(b * N_ + j0 + lg * 4 + r) * C_ + n0 + nb * 16 + lr];

  f32x4 mx[2];
#pragma unroll
  for (int nb = 0; nb < 2; ++nb)
#pragma unroll
    for (int r = 0; r < 4; ++r) mx[nb][r] = -INFINITY;

  const char* gedge = (const char*)(edge + ((size_t)(b * N_ + s) * N_ + j0) * C_);

  int soff[2];
#pragma unroll
  for (int q = 0; q < 2; ++q) {
    int y = w * 2048 + q * 1024 + lane * 16;
    int row = y >> 9;
    soff[q] = y ^ ((row & 7) << 4);
  }
  const int base0 = lr * 512 + lg * 32;
  const int swz = (lr & 7) << 4;
  // j-rows this lane's two GLLs cover (512B per row within the 8KB chunk)
  const int jrow0 = w * 4 + (lane >> 5);
  const int jrow1 = jrow0 + 2;
  const char* dummy = (const char*)ws_zero + lane * 16;

#define GLL16(GP, LP) __builtin_amdgcn_global_load_lds((gas_void*)(GP), (las_void*)(LP), 16, 0, 0)
#define GLL4(GP, LP)  __builtin_amdgcn_global_load_lds((gas_void*)(GP), (las_void*)(LP), 4, 0, 0)

#define ISSUE(SL, TT) do { \
    const char* gch = gedge + (size_t)(TT) * 8 * STEPB; \
    char* lb = ring + (SL) * 8192 + w * 2048; \
    GLL16(gch + soff[0], lb); \
    GLL16(gch + soff[1], lb + 1024); \
  } while (0)

  // masked variant: adj for step TT already in LDS (staged in prologue)
#define ISSUEM(SL, TT) do { \
    const char* gch = gedge + (size_t)(TT) * 8 * STEPB; \
    char* lb = ring + (SL) * 8192 + w * 2048; \
    unsigned char av0 = *(const unsigned char*)(adj_lds + (TT) * 16 + jrow0); \
    unsigned char av1 = *(const unsigned char*)(adj_lds + (TT) * 16 + jrow1); \
    GLL16(av0 ? gch + soff[0] : dummy, lb); \
    GLL16(av1 ? gch + soff[1] : dummy, lb + 1024); \
  } while (0)

#define STEP(SL, ISL, WAITN, DOISSUE, TI, T) do { \
    asm volatile("s_waitcnt vmcnt(" WAITN ")\n\ts_barrier" ::: "memory"); \
    if (DOISSUE) ISSUEM(ISL, TI); \
    const char* rb = ring + (SL) * 8192; \
    s16x8 af[4]; \
    _Pragma("unroll") \
    for (int kb = 0; kb < 4; ++kb) { \
      int a0 = (base0 + kb * 128) ^ swz; \
      f32x4 lo = *reinterpret_cast<const f32x4*>(rb + a0); \
      f32x4 hi = *reinterpret_cast<const f32x4*>(rb + (a0 ^ 16)); \
      af[kb] = cvt8(lo, hi); \
    } \
    unsigned int mw = *reinterpret_cast<const unsigned int*>(mh_lds + (T) * 256 + w * 64 + lr * 4); \
    unsigned int ab = *reinterpret_cast<const unsigned int*>(adj_lds + (T) * 16 + lg * 4); \
    float mh0 = __builtin_bit_cast(float, mw << 16); \
    float mh1 = __builtin_bit_cast(float, mw & 0xffff0000u); \
    float adjf[4] = {(float)(ab & 0xff), (float)((ab >> 8) & 0xff), \
                     (float)((ab >> 16) & 0xff), (float)(ab >> 24)}; \
    _Pragma("unroll") \
    for (int nb = 0; nb < 2; ++nb) { \
      f32x4 acc; \
      float mhv = nb ? mh1 : mh0; \
      _Pragma("unroll") \
      for (int r = 0; r < 4; ++r) acc[r] = cf[nb][r] + mhv; \
      _Pragma("unroll") \
      for (int kb = 0; kb < 4; ++kb) \
        acc = __builtin_amdgcn_mfma_f32_16x16x32_bf16(af[kb], bfrag[kb][nb], acc, 0, 0, 0); \
      _Pragma("unroll") \
      for (int r = 0; r < 4; ++r) mx[nb][r] = fmaxf(mx[nb][r], adjf[r] * acc[r]); \
    } \
  } while (0)

  {
    const char* mh_g = (const char*)(ws_mh2 + (size_t)b * N_ * C_);
#pragma unroll
    for (int q = 0; q < 2; ++q) {
      int T = w * 8 + q * 4 + (lane >> 4);
      GLL16(mh_g + ((size_t)(s + 8 * T)) * 256 + (lane & 15) * 16,
            mh_lds + w * 2048 + q * 1024);
    }
    const char* adj_g = (const char*)(ws_adj + (size_t)b * N_ * N_ + j0);
    GLL4(adj_g + ((size_t)(s + 8 * (lane >> 2))) * N_ + (lane & 3) * 4, adj_lds);
    GLL4(adj_g + ((size_t)(s + 8 * (16 + (lane >> 2)))) * N_ + (lane & 3) * 4, adj_lds + 256);
  }
  // gens 0,1 unmasked (adj not yet in LDS) — ~6% of traffic, correctness
  // unaffected (compute multiplies by adjf regardless)
  ISSUE(0, 0);
  ISSUE(1, 1);
  asm volatile("s_waitcnt vmcnt(4)\n\ts_barrier" ::: "memory");

  for (int o = 0; o < 10; ++o) {
    STEP(0, 2, "2", 1, 3 * o + 2, 3 * o);
    STEP(1, 0, "2", 1, 3 * o + 3, 3 * o + 1);
    STEP(2, 1, "2", 1, 3 * o + 4, 3 * o + 2);
  }
  STEP(0, 2, "2", 0, 0, 30);
  STEP(1, 0, "0", 0, 0, 31);

#undef STEP
#undef ISSUEM
#undef ISSUE
#undef GLL16
#undef GLL4

  float* prow = pbuf + (((size_t)s * B_ + b) * N_ + j0 + lg * 4) * C_ + n0 + lr;
#pragma unroll
  for (int nb = 0; nb < 2; ++nb)
#pragma unroll
    for (int r = 0; r < 4; ++r)
      prow[r * C_ + nb * 16] = mx[nb][r];
}

// ---------- Epilogue: S-max + node@Wo1 + hidden@Wo2 + msgs@Wo3 (proven) ----------
__global__ void k_epi(const float* __restrict__ node, const float* __restrict__ hidden,
                      const float* __restrict__ Wo1, const float* __restrict__ bo1,
                      const float* __restrict__ Wo2, const float* __restrict__ bo2,
                      const float* __restrict__ Wo3, const float* __restrict__ bo3,
                      const float* __restrict__ pbuf, float* __restrict__ out) {
  int row0 = blockIdx.x * 4;
  int col = threadIdx.x & 127;
  int half = threadIdx.x >> 7;
  __shared__ float shn[4][C_], shh[4][C_], shm[4][C_];
#pragma unroll
  for (int r = 0; r < 2; ++r) {
    int rr = half * 2 + r;
    shn[rr][col] = node[(row0 + rr) * C_ + col];
    shh[rr][col] = hidden[(row0 + rr) * C_ + col];
    float mv = -INFINITY;
#pragma unroll
    for (int s = 0; s < S_; ++s)
      mv = fmaxf(mv, pbuf[((size_t)s * (B_ * N_) + row0 + rr) * C_ + col]);
    shm[rr][col] = mv;
  }
  __syncthreads();
  float init = bo1[col] + bo2[col] + bo3[col];
  float acc[2];
  acc[0] = init; acc[1] = init;
  for (int k = 0; k < C_; k += 8) {
    float wv1[8], wv2[8], wv3[8];
#pragma unroll
    for (int u = 0; u < 8; ++u) {
      wv1[u] = Wo1[(k + u) * C_ + col];
      wv2[u] = Wo2[(k + u) * C_ + col];
      wv3[u] = Wo3[(k + u) * C_ + col];
    }
#pragma unroll
    for (int u = 0; u < 8; ++u)
#pragma unroll
      for (int r = 0; r < 2; ++r) {
        int rr = half * 2 + r;
        acc[r] += shn[rr][k + u] * wv1[u] + shh[rr][k + u] * wv2[u] + shm[rr][k + u] * wv3[u];
      }
  }
#pragma unroll
  for (int r = 0; r < 2; ++r)
    out[(row0 + half * 2 + r) * C_ + col] = acc[r];
}

extern "C" void kernel_launch(void* const* d_in, const int* in_sizes, int n_in,
                              void* d_out, int out_size, void* d_ws, size_t ws_size,
                              hipStream_t stream) {
  const float* node   = (const float*)d_in[0];
  const float* edge   = (const float*)d_in[1];
  const float* graph  = (const float*)d_in[2];
  const int*   adjm   = (const int*)d_in[3];
  const float* hidden = (const float*)d_in[4];
  const float* Wn = (const float*)d_in[5];  const float* bn = (const float*)d_in[6];
  const float* Wh = (const float*)d_in[7];  const float* bh = (const float*)d_in[8];
  const float* We = (const float*)d_in[9];  const float* be = (const float*)d_in[10];
  const float* Wg = (const float*)d_in[11]; const float* bg = (const float*)d_in[12];
  const float* Wo1 = (const float*)d_in[13]; const float* bo1 = (const float*)d_in[14];
  const float* Wo2 = (const float*)d_in[15]; const float* bo2 = (const float*)d_in[16];
  const float* Wo3 = (const float*)d_in[17]; const float* bo3 = (const float*)d_in[18];
  float* out = (float*)d_out;

  char* ws = (char*)d_ws;
  float*          ws_c   = (float*)ws;                            // 1 MB
  unsigned short* ws_mh2 = (unsigned short*)(ws + (1u << 20));    // 512 KB (bf16)
  short*          ws_B   = (short*)(ws + 1572864u);               // 32 KB
  unsigned char*  ws_adj = (unsigned char*)(ws + 1835008u);       // 512 KB
  float*          ws_zero= (float*)(ws + (3u << 20));             // 1 KB zeros
  float*          pbuf   = (float*)(ws + (4u << 20));             // 8 MB partials (f32)

  k_pro<<<1057, 128, 0, stream>>>(node, hidden, graph, adjm, Wn, bn, Wh, bh, be,
                                  Wg, bg, We, ws_c, ws_mh2, ws_B, ws_adj, ws_zero);
  k_main<<<1024, 256, 0, stream>>>(edge, ws_adj, ws_B, ws_c, ws_mh2, ws_zero, pbuf);
  k_epi<<<512, 256, 0, stream>>>(node, hidden, Wo1, bo1, Wo2, bo2, Wo3, bo3,
                                 pbuf, out);
}